// Round 1
// baseline (625.692 us; speedup 1.0000x reference)
//
#include <hip/hip_runtime.h>

// Problem constants
#define HW_   53568                 // 248*216
#define B_    4
#define CIN_  384
#define NPOS_ (B_ * HW_)            // 214272
#define CHW_  (CIN_ * HW_)          // 20,570,112
#define NOUT_ 20                    // 2 cls + 14 reg + 4 dir
#define NW_   (CIN_ * NOUT_)        // 7680 combined weights
#define TPB_  128                   // threads per block
#define PPT_  4                     // positions per thread
#define NBLK_ 512                   // exactly 2 blocks/CU on 256 CUs
#define PPB_  419                   // ceil(NPOS_/NBLK_) positions per block

// Build combined weight matrix wcomb[c][o] (o: 0-1 cls, 2-15 reg, 16-19 dir),
// rows are 80 B (16B-aligned for float4 reads). Biases appended at NW_.
__global__ void prep_weights(const float* __restrict__ w_cls,
                             const float* __restrict__ b_cls,
                             const float* __restrict__ w_reg,
                             const float* __restrict__ b_reg,
                             const float* __restrict__ w_dir,
                             const float* __restrict__ b_dir,
                             float* __restrict__ wcomb) {
    int idx = blockIdx.x * blockDim.x + threadIdx.x;
    if (idx < NW_) {
        int c = idx / NOUT_;
        int o = idx - c * NOUT_;
        float v;
        if (o < 2)       v = w_cls[c * 2  + o];
        else if (o < 16) v = w_reg[c * 14 + (o - 2)];
        else             v = w_dir[c * 4  + (o - 16)];
        wcomb[idx] = v;
    } else if (idx < NW_ + NOUT_) {
        int o = idx - NW_;
        float v;
        if (o < 2)       v = b_cls[o];
        else if (o < 16) v = b_reg[o - 2];
        else             v = b_dir[o - 16];
        wcomb[idx] = v;
    }
}

__global__ __launch_bounds__(TPB_) void head_fused(
        const float* __restrict__ x,
        const float* __restrict__ wcomb,
        float* __restrict__ out) {
    __shared__ __align__(16) float lw[NW_ + NOUT_];   // 30800 B
    for (int i = threadIdx.x; i < NW_ + NOUT_; i += TPB_)
        lw[i] = wcomb[i];
    __syncthreads();

    const int base  = (int)blockIdx.x * PPB_;
    const int limit = min(base + PPB_, NPOS_);

    const float* xb[PPT_];
    int  bi[PPT_], si[PPT_];
    bool valid[PPT_];
#pragma unroll
    for (int j = 0; j < PPT_; ++j) {
        int p = base + j * TPB_ + (int)threadIdx.x;
        valid[j] = (p < limit);
        unsigned pp = valid[j] ? (unsigned)p : 0u;   // dummy lanes read pos 0 (cached)
        unsigned b = pp / HW_;
        unsigned s = pp - b * HW_;
        bi[j] = (int)b;
        si[j] = (int)s;
        xb[j] = x + (size_t)b * CHW_ + s;
    }

    float acc[PPT_][NOUT_];
#pragma unroll
    for (int j = 0; j < PPT_; ++j)
#pragma unroll
        for (int o = 0; o < NOUT_; ++o) acc[j][o] = 0.0f;

    // Hot loop: 1 coalesced dword load per position per channel,
    // 5 broadcast float4 LDS reads, 80 FMAs per thread per channel.
#pragma unroll 4
    for (int c = 0; c < CIN_; ++c) {
        float xv[PPT_];
#pragma unroll
        for (int j = 0; j < PPT_; ++j)
            xv[j] = xb[j][(size_t)c * HW_];
        const float4* wr = (const float4*)&lw[c * NOUT_];
#pragma unroll
        for (int q = 0; q < 5; ++q) {
            float4 w = wr[q];
#pragma unroll
            for (int j = 0; j < PPT_; ++j) {
                acc[j][4 * q + 0] += w.x * xv[j];
                acc[j][4 * q + 1] += w.y * xv[j];
                acc[j][4 * q + 2] += w.z * xv[j];
                acc[j][4 * q + 3] += w.w * xv[j];
            }
        }
    }

    float* out_cls = out;
    float* out_reg = out + (size_t)B_ * 2 * HW_;
    float* out_dir = out + (size_t)B_ * 2 * HW_ + (size_t)B_ * 14 * HW_;
#pragma unroll
    for (int j = 0; j < PPT_; ++j) {
        if (!valid[j]) continue;
        int b = bi[j], s = si[j];
#pragma unroll
        for (int o = 0; o < 2; ++o)
            out_cls[(size_t)(b * 2 + o) * HW_ + s] = acc[j][o] + lw[NW_ + o];
#pragma unroll
        for (int o = 0; o < 14; ++o)
            out_reg[(size_t)(b * 14 + o) * HW_ + s] = acc[j][2 + o] + lw[NW_ + 2 + o];
#pragma unroll
        for (int o = 0; o < 4; ++o)
            out_dir[(size_t)(b * 4 + o) * HW_ + s] = acc[j][16 + o] + lw[NW_ + 16 + o];
    }
}

extern "C" void kernel_launch(void* const* d_in, const int* in_sizes, int n_in,
                              void* d_out, int out_size, void* d_ws, size_t ws_size,
                              hipStream_t stream) {
    const float* x     = (const float*)d_in[0];
    const float* w_cls = (const float*)d_in[1];
    const float* b_cls = (const float*)d_in[2];
    const float* w_reg = (const float*)d_in[3];
    const float* b_reg = (const float*)d_in[4];
    const float* w_dir = (const float*)d_in[5];
    const float* b_dir = (const float*)d_in[6];
    float* out   = (float*)d_out;
    float* wcomb = (float*)d_ws;    // needs 30800 B

    prep_weights<<<(NW_ + NOUT_ + 255) / 256, 256, 0, stream>>>(
        w_cls, b_cls, w_reg, b_reg, w_dir, b_dir, wcomb);
    head_fused<<<NBLK_, TPB_, 0, stream>>>(x, wcomb, out);
}